// Round 4
// baseline (65.991 us; speedup 1.0000x reference)
//
#include <hip/hip_runtime.h>

#define BLK 1024

// minimax atan2, max err ~2e-6 rad; inputs never both zero here
__device__ __forceinline__ float fast_atan2f(float y, float x) {
    float ax = __builtin_fabsf(x), ay = __builtin_fabsf(y);
    float mx = fmaxf(ax, ay), mn = fminf(ax, ay);
    float a  = mn * __builtin_amdgcn_rcpf(mx);
    float s  = a * a;
    float r  = fmaf(s, -0.0117212f,  0.05265332f);
    r = fmaf(s, r, -0.11643287f);
    r = fmaf(s, r,  0.19354346f);
    r = fmaf(s, r, -0.33262347f);
    r = fmaf(s, r,  0.99997726f);
    r *= a;
    if (ay > ax)  r = 1.57079637f - r;
    if (x < 0.0f) r = 3.14159274f - r;
    return copysignf(r, y);
}

__global__ __launch_bounds__(BLK)
void equil_kernel(const float* __restrict__ pos0,
                  const float* __restrict__ tip_pos,
                  const float* __restrict__ thetas_ss,
                  const int*   __restrict__ buckle,
                  const float* __restrict__ kstiff_p,
                  const float* __restrict__ ksoft_p,
                  const float* __restrict__ kstretch_p,
                  float* __restrict__ out)
{
    // tiny cross-wave staging only
    __shared__ float2 bM[16][2];   // [w]: myp of lanes 62,63 (nodes 64w+64, 64w+65)
    __shared__ float2 bP[17][2];   // [w]: P of lanes 0,1 of wave w; bP[16][0] = S_1024
    __shared__ float2 bQ[17];      // [w]: Q of lane 0 of wave w

    const int b  = blockIdx.x;
    const int t  = threadIdx.x;
    const int wv = t >> 6, ln = t & 63;
    const float k_str  = kstretch_p[0];
    const float k_sd   = kstiff_p[0] - ksoft_p[0];
    const float k4soft = 4.0f * ksoft_p[0];

    const float2* p0 = (const float2*)(pos0 + (size_t)b * 2052);
    const float2 c0 = p0[0], c1 = p0[1];           // fixed nodes 0,1
    float2 tip; tip.x = tip_pos[2*b]; tip.y = tip_pos[2*b+1];   // fixed node 1025

    // thread t: computes angle t, owns node t+2 (free for t<=1022)
    float2 myp = (t < 1023) ? p0[t + 2] : tip;

    const float TH = thetas_ss[t];
    const int4 bk  = ((const int4*)buckle)[t];
    const float npl = (float)(bk.x + bk.y + bk.z + bk.w);
    float2 vel = make_float2(0.f, 0.f);

    if (ln >= 62) bM[wv][ln - 62] = myp;
    __syncthreads();

    for (int s = 0; s < 64; ++s) {
        // ---- phase AB: angle t from nodes t,t+1,t+2 = myp@(t-2),@(t-1),own ----
        float2 pm1, pm2;
        pm1.x = __shfl_up(myp.x, 1, 64);  pm1.y = __shfl_up(myp.y, 1, 64);
        pm2.x = __shfl_up(myp.x, 2, 64);  pm2.y = __shfl_up(myp.y, 2, 64);
        if (ln == 0) {
            pm1 = wv ? bM[wv-1][1] : c1;
            pm2 = wv ? bM[wv-1][0] : c0;
        } else if (ln == 1) {
            pm2 = wv ? bM[wv-1][1] : c1;
        }
        float v1x = pm1.x - pm2.x, v1y = pm1.y - pm2.y;
        float v2x = myp.x - pm1.x, v2y = myp.y - pm1.y;
        float l2a = fmaf(v1x, v1x, v1y * v1y);
        float l2b = fmaf(v2x, v2x, v2y * v2y);
        float cr  = v1x * v2y - v1y * v2x;
        float dt_ = fmaf(v1x, v2x, v1y * v2y);
        float theta = fast_atan2f(cr, dt_);
        float cnt = (theta <  TH ? npl        : 0.f)
                  + (theta > -TH ? 4.f - npl  : 0.f);
        float K = fmaf(cnt, k_sd, k4soft);
        float m = K * (theta - TH);
        float ila = __builtin_amdgcn_rsqf(l2a);
        float ilb = __builtin_amdgcn_rsqf(l2b);
        float m1 = m * ila * ila;
        float m2 = m * ilb * ilb;
        float2 Bv; Bv.x = -m2 * v2y;  Bv.y =  m2 * v2x;     // b_t
        float sca = k_str * (1.0f - ila);
        float2 P;  P.x = fmaf(sca, v1x,  m1 * v1y);         // S_t + a_t
        P.y = fmaf(sca, v1y, -m1 * v1x);
        float2 Q;  Q.x = P.x - Bv.x;  Q.y = P.y - Bv.y;     // S_t + a_t - b_t
        if (ln == 0)      { bP[wv][0] = P; bQ[wv] = Q; }
        else if (ln == 1) { bP[wv][1] = P; }
        if (t == 1023) {   // publish P[1024] = S_1024 (no angle 1024)
            float scb = k_str * (1.0f - ilb);
            float2 PN; PN.x = scb * v2x; PN.y = scb * v2y;
            bP[16][0] = PN;
        }
        __syncthreads();

        // ---- phase C: f(node t+2) = P[t+2] - Q[t+1] - B[t] ----
        float2 Pn, Qm;
        Pn.x = __shfl_down(P.x, 2, 64);  Pn.y = __shfl_down(P.y, 2, 64);
        Qm.x = __shfl_down(Q.x, 1, 64);  Qm.y = __shfl_down(Q.y, 1, 64);
        if (ln == 62)      { Pn = bP[wv+1][0]; }
        else if (ln == 63) { Pn = bP[wv+1][1]; Qm = bQ[wv+1]; }
        if (t < 1023) {
            float fx = Pn.x - Qm.x - Bv.x;
            float fy = Pn.y - Qm.y - Bv.y;
            vel.x += 0.001f * (fx - 2.0f * vel.x);
            vel.y += 0.001f * (fy - 2.0f * vel.y);
            myp.x += 0.001f * vel.x;
            myp.y += 0.001f * vel.y;
        }
        if (ln >= 62) bM[wv][ln - 62] = myp;
        __syncthreads();
    }

    // ---- epilogue ----
    float2* o = (float2*)(out + (size_t)b * 2052);
    o[t + 2] = myp;          // t=1023 writes node 1025 = tip
    if (t == 0) o[0] = c0;
    if (t == 1) o[1] = c1;
}

extern "C" void kernel_launch(void* const* d_in, const int* in_sizes, int n_in,
                              void* d_out, int out_size, void* d_ws, size_t ws_size,
                              hipStream_t stream) {
    const float* pos0   = (const float*)d_in[0];
    const float* tip    = (const float*)d_in[1];
    const float* thetas = (const float*)d_in[2];
    const int*   buckle = (const int*)  d_in[3];
    const float* ks     = (const float*)d_in[4];
    const float* ko     = (const float*)d_in[5];
    const float* kr     = (const float*)d_in[6];
    float* out = (float*)d_out;
    hipLaunchKernelGGL(equil_kernel, dim3(256), dim3(BLK), 0, stream,
                       pos0, tip, thetas, buckle, ks, ko, kr, out);
}

// Round 5
// 46.050 us; speedup vs baseline: 1.4330x; 1.4330x over previous
//
#include <hip/hip_runtime.h>

#define NN 1026   // nodes per chain
#define NE 1025   // edges
#define NA 1024   // angles
#define BLK 1024

// minimax atan2, max err ~2e-6 rad; inputs never both zero here
__device__ __forceinline__ float fast_atan2f(float y, float x) {
    float ax = __builtin_fabsf(x), ay = __builtin_fabsf(y);
    float mx = fmaxf(ax, ay), mn = fminf(ax, ay);
    float a  = mn * __builtin_amdgcn_rcpf(mx);
    float s  = a * a;
    float r  = fmaf(s, -0.0117212f,  0.05265332f);
    r = fmaf(s, r, -0.11643287f);
    r = fmaf(s, r,  0.19354346f);
    r = fmaf(s, r, -0.33262347f);
    r = fmaf(s, r,  0.99997726f);
    r *= a;
    if (ay > ax)  r = 1.57079637f - r;
    if (x < 0.0f) r = 3.14159274f - r;
    return copysignf(r, y);
}

__global__ __launch_bounds__(BLK)
void equil_kernel(const float* __restrict__ pos0,
                  const float* __restrict__ tip_pos,
                  const float* __restrict__ thetas_ss,
                  const int*   __restrict__ buckle,
                  const float* __restrict__ kstiff_p,
                  const float* __restrict__ ksoft_p,
                  const float* __restrict__ kstretch_p,
                  float* __restrict__ out)
{
    __shared__ float2 pos[NN];   // node positions (pos[1025] static = tip)
    __shared__ float2 Ps[NE];    // P_j = S_j + a_j   (P[1024] = S_1024)
    __shared__ float2 Qs[NA];    // Q_j = S_j + a_j - b_j

    const int b   = blockIdx.x;
    const int t   = threadIdx.x;
    const float k_str  = kstretch_p[0];
    const float k_sd   = kstiff_p[0] - ksoft_p[0];
    const float k4soft = 4.0f * ksoft_p[0];

    // ---- init ----
    const float2* p0 = (const float2*)(pos0 + (size_t)b * NN * 2);
    // thread t computes angle t, owns node t+2 (free for t<=1022; t=1023 -> tip)
    float2 myp;
    if (t < 1023) {
        myp = p0[t + 2];
    } else {
        myp.x = tip_pos[2*b];  myp.y = tip_pos[2*b+1];
    }
    pos[t + 2] = myp;
    if (t < 2) pos[t] = p0[t];     // fixed nodes 0,1

    const float TH = thetas_ss[t];
    const int4 bk  = ((const int4*)buckle)[t];
    const float npl = (float)(bk.x + bk.y + bk.z + bk.w);   // #(pm==+1)
    float2 vel = make_float2(0.f, 0.f);
    __syncthreads();

    for (int s = 0; s < 64; ++s) {
        // ---- phase AB: angle t from pos[t], pos[t+1], own myp ----
        float2 pa = pos[t], pb = pos[t+1];
        float v1x = pb.x - pa.x,  v1y = pb.y - pa.y;
        float v2x = myp.x - pb.x, v2y = myp.y - pb.y;
        float l2a = fmaf(v1x, v1x, v1y * v1y);
        float l2b = fmaf(v2x, v2x, v2y * v2y);
        float cr  = v1x * v2y - v1y * v2x;
        float dt_ = fmaf(v1x, v2x, v1y * v2y);
        float theta = fast_atan2f(cr, dt_);
        float cnt = (theta <  TH ? npl        : 0.f)
                  + (theta > -TH ? 4.f - npl  : 0.f);
        float K = fmaf(cnt, k_sd, k4soft);
        float m = K * (theta - TH);
        float ila = __builtin_amdgcn_rsqf(l2a);
        float ilb = __builtin_amdgcn_rsqf(l2b);
        float m1 = m * ila * ila;                 // m / l2a
        float m2 = m * ilb * ilb;                 // m / l2b
        float2 Bv; Bv.x = -m2 * v2y;  Bv.y =  m2 * v2x;     // b_t (register only)
        float sca = k_str * (1.0f - ila);                   // k*(len_a-1)/len_a
        float2 P;  P.x = fmaf(sca, v1x,  m1 * v1y);         // S_t + a_t
                   P.y = fmaf(sca, v1y, -m1 * v1x);
        float2 Q;  Q.x = P.x - Bv.x;  Q.y = P.y - Bv.y;
        Ps[t] = P;
        Qs[t] = Q;
        if (t == NA - 1) {   // P[1024] = S_1024 (stretch only, no angle 1024)
            float scb = k_str * (1.0f - ilb);
            float2 PN; PN.x = scb * v2x; PN.y = scb * v2y;
            Ps[NA] = PN;
        }
        __syncthreads();

        // ---- phase C: f(node t+2) = P[t+2] - Q[t+1] - B[t](register) ----
        if (t < 1023) {
            float2 Pn = Ps[t+2];
            float2 Qm = Qs[t+1];
            float fx = Pn.x - Qm.x - Bv.x;
            float fy = Pn.y - Qm.y - Bv.y;
            vel.x += 0.001f * (fx - 2.0f * vel.x);
            vel.y += 0.001f * (fy - 2.0f * vel.y);
            myp.x += 0.001f * vel.x;
            myp.y += 0.001f * vel.y;
            pos[t + 2] = myp;
        }
        __syncthreads();
    }

    // ---- epilogue ----
    float2* o = (float2*)(out + (size_t)b * NN * 2);
    o[t + 2] = myp;          // t=1023 writes node 1025 = tip
    if (t < 2) o[t] = pos[t];
}

extern "C" void kernel_launch(void* const* d_in, const int* in_sizes, int n_in,
                              void* d_out, int out_size, void* d_ws, size_t ws_size,
                              hipStream_t stream) {
    const float* pos0   = (const float*)d_in[0];
    const float* tip    = (const float*)d_in[1];
    const float* thetas = (const float*)d_in[2];
    const int*   buckle = (const int*)  d_in[3];
    const float* ks     = (const float*)d_in[4];
    const float* ko     = (const float*)d_in[5];
    const float* kr     = (const float*)d_in[6];
    float* out = (float*)d_out;
    hipLaunchKernelGGL(equil_kernel, dim3(256), dim3(BLK), 0, stream,
                       pos0, tip, thetas, buckle, ks, ko, kr, out);
}